// Round 1
// 354.301 us; speedup vs baseline: 1.1470x; 1.1470x over previous
//
#include <hip/hip_runtime.h>

#define N_  64
#define CI  256
#define CO  256
#define CR  32
#define T_  64
#define V_  25
#define TV  (T_*V_)   // 1600
#define VV  (V_*V_)   // 625
#define ATS 640       // attnT per-(n,o) stride in shorts (625 used, pad to 16B-aligned)

typedef __attribute__((ext_vector_type(8))) short bshort8;
typedef __attribute__((ext_vector_type(4))) short bshort4;
typedef __attribute__((ext_vector_type(4))) float f32x4;

__device__ inline unsigned short f2bf(float f) {
    unsigned int u = __float_as_uint(f);
    return (unsigned short)((u + 0x7FFFu + ((u >> 16) & 1u)) >> 16);
}

// ---------------- K0: w3 -> bf16 in MFMA A-fragment order ----------------
// w3f[((ot*8+ks)*64+lane)*8+i] = w3[ot*16+(lane&15)][ks*32+(lane>>4)*8+i]
__global__ __launch_bounds__(256) void k_cvt_w3f(const float* __restrict__ w3,
                                                 unsigned short* __restrict__ w3f) {
    int f = blockIdx.x * 256 + threadIdx.x;        // 0..8191
    int lane = f & 63;
    int ks = (f >> 6) & 7;
    int ot = f >> 9;
    const float* src = w3 + (size_t)(ot * 16 + (lane & 15)) * CI + ks * 32 + (lane >> 4) * 8;
    bshort8 v;
    #pragma unroll
    for (int i = 0; i < 8; ++i) v[i] = (short)f2bf(src[i]);
    *(bshort8*)(w3f + (size_t)f * 8) = v;
}

// ---------------- K0b: w4 -> bf16 in MFMA A-fragment order ----------------
// w4f[(ot*64+lane)*8+i] = w4[ot*16+(lane&15)][(lane>>4)*8+i]   (K = CR = 32 exactly)
__global__ __launch_bounds__(256) void k_cvt_w4f(const float* __restrict__ w4,
                                                 unsigned short* __restrict__ w4f) {
    int f = blockIdx.x * 256 + threadIdx.x;        // 0..1023 (16 o-tiles * 64 lanes)
    int lane = f & 63;
    int ot = f >> 6;
    const float* src = w4 + (size_t)(ot * 16 + (lane & 15)) * CR + (lane >> 4) * 8;
    bshort8 v;
    #pragma unroll
    for (int i = 0; i < 8; ++i) v[i] = (short)f2bf(src[i]);
    *(bshort8*)(w4f + (size_t)f * 8) = v;
}

// ---------------- K1: xm[n,c,v] = mean_t x[n,c,t,v] ----------------
__global__ __launch_bounds__(256) void k_mean(const float* __restrict__ x,
                                              float* __restrict__ xm) {
    int idx = blockIdx.x * 256 + threadIdx.x;
    if (idx >= N_ * CI * V_) return;
    int v  = idx % V_;
    int nc = idx / V_;
    const float* p = x + (size_t)nc * TV + v;
    float s = 0.f;
    for (int t = 0; t < T_; ++t) s += p[t * V_];
    xm[idx] = s * (1.f / T_);
}

// ---------------- K1b: x[n,c,j] -> xT_bf[n,j,c] ----------------
__global__ __launch_bounds__(256) void k_xpose(const float* __restrict__ x,
                                               unsigned short* __restrict__ xT) {
    int n  = blockIdx.x;
    int c0 = blockIdx.y * 64;
    int j0 = blockIdx.z * 64;
    __shared__ float L[64 * 65];
    int tid = threadIdx.x;
    #pragma unroll
    for (int p = 0; p < 4; ++p) {
        int cc = p * 16 + (tid >> 4);
        int f4 = tid & 15;
        float4 v = *(const float4*)(x + (size_t)n * CI * TV + (size_t)(c0 + cc) * TV + j0 + f4 * 4);
        L[(f4 * 4 + 0) * 65 + cc] = v.x;
        L[(f4 * 4 + 1) * 65 + cc] = v.y;
        L[(f4 * 4 + 2) * 65 + cc] = v.z;
        L[(f4 * 4 + 3) * 65 + cc] = v.w;
    }
    __syncthreads();
    int jl = tid >> 2, seg = tid & 3;
    bshort8 o0v, o1v;
    #pragma unroll
    for (int q = 0; q < 8; ++q) o0v[q] = (short)f2bf(L[jl * 65 + seg * 16 + q]);
    #pragma unroll
    for (int q = 0; q < 8; ++q) o1v[q] = (short)f2bf(L[jl * 65 + seg * 16 + 8 + q]);
    unsigned short* dst = xT + (size_t)n * (TV * CI) + (size_t)(j0 + jl) * CI + c0 + seg * 16;
    *(bshort8*)dst = o0v;
    *(bshort8*)(dst + 8) = o1v;
}

// ---------------- K2: x1/x2 = w1/w2 @ xm + b ----------------
__global__ __launch_bounds__(256) void k_x1x2(const float* __restrict__ xm,
                                              const float* __restrict__ w1,
                                              const float* __restrict__ b1,
                                              const float* __restrict__ w2,
                                              const float* __restrict__ b2,
                                              float* __restrict__ x1,
                                              float* __restrict__ x2) {
    int n = blockIdx.x;
    __shared__ float s_xm[CI * V_];
    const float4* src = (const float4*)(xm + (size_t)n * CI * V_);
    for (int i = threadIdx.x; i < CI * V_ / 4; i += 256) ((float4*)s_xm)[i] = src[i];
    __syncthreads();
    for (int idx = threadIdx.x; idx < CR * V_; idx += 256) {
        int r = idx / V_, v = idx % V_;
        float a1 = 0.f, a2 = 0.f;
        for (int c = 0; c < CI; ++c) {
            float xv = s_xm[c * V_ + v];
            a1 += w1[r * CI + c] * xv;
            a2 += w2[r * CI + c] * xv;
        }
        x1[n * CR * V_ + idx] = a1 + b1[r];
        x2[n * CR * V_ + idx] = a2 + b2[r];
    }
}

// ---------------- K3: attnT bf16 via MFMA, aff computed in registers ----------------
// attnT[v][u] at uv=v*25+u: (sum_r w4[o,r]*tanh(x1[r,u]-x2[r,v]) + b4[o])*alpha + A[u,v]
// wave-task = 4 o-tiles (64 o) x 5 uv-tiles (80 uv cols); grid (n, 8) -> 512 blocks
__global__ __launch_bounds__(256) void k_attn(const float* __restrict__ x1,
                                              const float* __restrict__ x2,
                                              const unsigned short* __restrict__ w4f,
                                              const float* __restrict__ b4,
                                              const float* __restrict__ A,
                                              const int* __restrict__ alpha_p,
                                              unsigned short* __restrict__ attnT) {
    int n = blockIdx.x;
    __shared__ float s_x1[CR * V_];
    __shared__ float s_x2[CR * V_];
    __shared__ float s_A[VV];
    int tid = threadIdx.x;
    float alpha = (float)alpha_p[0];
    for (int i = tid; i < CR * V_; i += 256) {
        s_x1[i] = x1[n * CR * V_ + i];
        s_x2[i] = x2[n * CR * V_ + i];
    }
    for (int i = tid; i < VV; i += 256) s_A[i] = A[i];
    __syncthreads();
    int wave = tid >> 6, lane = tid & 63;
    int task = blockIdx.y * 4 + wave;       // 0..31
    int og   = task & 3;                    // o-group of 64 (4 MFMA o-tiles)
    int ug   = task >> 2;                   // uv-group of 5 uv-tiles (80 cols)
    int o0   = og * 64;
    int quad = lane >> 4, c16 = lane & 15;
    // A-frags: lane holds w4[o0+ot*16+(lane&15)][quad*8+i]
    bshort8 a[4];
    #pragma unroll
    for (int ot = 0; ot < 4; ++ot)
        a[ot] = *(const bshort8*)(w4f + (size_t)(((og * 4) + ot) * 64 + lane) * 8);
    // b4 for the 4 output rows this lane owns per o-tile
    float4 bv[4];
    #pragma unroll
    for (int ot = 0; ot < 4; ++ot)
        bv[ot] = *(const float4*)(b4 + o0 + ot * 16 + quad * 4);
    int r0 = quad * 8;
    #pragma unroll
    for (int it = 0; it < 5; ++it) {
        int uv0 = (ug * 5 + it) * 16;
        int uvc = uv0 + c16;
        bool valid = uvc < VV;
        int uvcc = valid ? uvc : (VV - 1);
        int u = uvcc % V_, v = uvcc / V_;
        // B-frag: lane holds aff[r = quad*8+i][uv col = c16], computed in registers
        bshort8 b;
        #pragma unroll
        for (int i = 0; i < 8; ++i) {
            float d = s_x1[(r0 + i) * V_ + u] - s_x2[(r0 + i) * V_ + v];
            b[i] = (short)f2bf(tanhf(d));
        }
        float Auv = s_A[u * V_ + v];
        f32x4 acc[4];
        #pragma unroll
        for (int ot = 0; ot < 4; ++ot)
            acc[ot] = __builtin_amdgcn_mfma_f32_16x16x32_bf16(a[ot], b, (f32x4){0,0,0,0}, 0, 0, 0);
        if (valid) {
            #pragma unroll
            for (int ot = 0; ot < 4; ++ot) {
                #pragma unroll
                for (int r = 0; r < 4; ++r) {
                    int o = o0 + ot * 16 + quad * 4 + r;
                    float bval = (r == 0) ? bv[ot].x : (r == 1) ? bv[ot].y
                               : (r == 2) ? bv[ot].z : bv[ot].w;
                    attnT[(size_t)(n * CO + o) * ATS + uvc] =
                        f2bf((acc[ot][r] + bval) * alpha + Auv);
                }
            }
        }
    }
}

// ---------------- K4: MFMA GEMM full-o: x3_bf[n,o,j] = bf16(w3 @ x + b3) ----------------
// block = (n, j-tile 64); o = 256; xT read ONCE; A-frags from fragment-ordered w3f (L2)
__global__ __launch_bounds__(256) void k_gemm1(const unsigned short* __restrict__ xT,
                                               const unsigned short* __restrict__ w3f,
                                               const float* __restrict__ b3,
                                               unsigned short* __restrict__ x3) {
    int n = blockIdx.x, j0 = blockIdx.y * 64;
    __shared__ unsigned short sB[64 * 256];
    int tid  = threadIdx.x;
    int lane = tid & 63, wave = tid >> 6;
    const unsigned short* gB = xT + (size_t)n * (TV * CI) + (size_t)j0 * CI;
    #pragma unroll
    for (int pp = 0; pp < 8; ++pp) {
        int task = pp * 256 + tid;
        int row = task >> 5, part = task & 31;
        int phys = part ^ (row & 7);
        *(bshort8*)(&sB[row * 256 + phys * 8]) = *(const bshort8*)(gB + row * 256 + part * 8);
    }
    __syncthreads();
    int quad = lane >> 4, c16 = lane & 15;
    const bshort8* Af = (const bshort8*)w3f;
    f32x4 acc[4][4];
    #pragma unroll
    for (int mt = 0; mt < 4; ++mt)
        #pragma unroll
        for (int nt = 0; nt < 4; ++nt) acc[mt][nt] = (f32x4){0,0,0,0};
    #pragma unroll
    for (int ks = 0; ks < 8; ++ks) {
        bshort8 b[4], a[4];
        #pragma unroll
        for (int nt = 0; nt < 4; ++nt) {
            int rB = nt * 16 + c16;
            int cidx = ks * 4 + quad;
            b[nt] = *(const bshort8*)(&sB[rB * 256 + ((cidx ^ (rB & 7)) << 3)]);
        }
        #pragma unroll
        for (int mt = 0; mt < 4; ++mt)
            a[mt] = Af[(size_t)(((wave * 4 + mt) * 8 + ks) * 64) + lane];
        #pragma unroll
        for (int mt = 0; mt < 4; ++mt)
            #pragma unroll
            for (int nt = 0; nt < 4; ++nt)
                acc[mt][nt] = __builtin_amdgcn_mfma_f32_16x16x32_bf16(a[mt], b[nt], acc[mt][nt], 0, 0, 0);
    }
    __syncthreads();                      // sB free; alias as epilogue buffer
    unsigned short* eS = sB;              // 128 rows x stride 72 shorts
    #pragma unroll
    for (int pass = 0; pass < 2; ++pass) {
        if ((wave >> 1) == pass) {
            #pragma unroll
            for (int mt = 0; mt < 4; ++mt) {
                int o = wave * 64 + mt * 16 + quad * 4;
                float4 bvv = *(const float4*)(b3 + o);
                int ol = (wave & 1) * 64 + mt * 16 + quad * 4;
                #pragma unroll
                for (int nt = 0; nt < 4; ++nt) {
                    int jc = nt * 16 + c16;
                    eS[(ol + 0) * 72 + jc] = f2bf(acc[mt][nt][0] + bvv.x);
                    eS[(ol + 1) * 72 + jc] = f2bf(acc[mt][nt][1] + bvv.y);
                    eS[(ol + 2) * 72 + jc] = f2bf(acc[mt][nt][2] + bvv.z);
                    eS[(ol + 3) * 72 + jc] = f2bf(acc[mt][nt][3] + bvv.w);
                }
            }
        }
        __syncthreads();
        #pragma unroll
        for (int i = 0; i < 4; ++i) {
            int task = i * 256 + tid;         // 1024
            int orow = task >> 3, seg = task & 7;
            bshort8 vv = *(const bshort8*)&eS[orow * 72 + seg * 8];
            *(bshort8*)(x3 + (size_t)(n * CO + pass * 128 + orow) * TV + j0 + seg * 8) = vv;
        }
        __syncthreads();
    }
}

// ---------------- K5: MFMA contraction: out[t,v] = sum_u x3[t,u] * attnT[v,u] ----------------
// block = 4 (n,o) pairs, one wave each; u padded to 32 (zeros in A and B pads)
__global__ __launch_bounds__(256) void k_contract(const unsigned short* __restrict__ x3,
                                                  const unsigned short* __restrict__ attnT,
                                                  float* __restrict__ out) {
    int no0 = blockIdx.x * 4;
    __shared__ __align__(16) unsigned char smem[28672];
    unsigned short* sA = (unsigned short*)smem;            // 4 x [64][32]
    unsigned short* sB = (unsigned short*)(smem + 16384);  // 4 x [32][32]
    float*          sO = (float*)smem;                     // 4 x [64][28]
    int tid = threadIdx.x;
    // zero u-pads
    #pragma unroll
    for (int i = 0; i < 7; ++i) {
        int task = i * 256 + tid;              // 4*64*7 = 1792
        if (task < 1792) {
            int p = task / 448, rem = task % 448;
            sA[p * 2048 + (rem / 7) * 32 + 25 + rem % 7] = 0;
        }
    }
    {
        int task = tid;                         // 4*25*7 = 700
        for (int i = 0; i < 3; ++i, task += 256)
            if (task < 700) {
                int p = task / 175, rem = task % 175;
                sB[p * 1024 + (rem / 7) * 32 + 25 + rem % 7] = 0;
            }
    }
    // stage x3 (scatter to u-stride 32)
    #pragma unroll
    for (int i = 0; i < 4; ++i) {
        int task = i * 256 + tid;              // 800
        if (task < 800) {
            int p = task / 200, e8 = task % 200;
            bshort8 vv = *(const bshort8*)(x3 + (size_t)(no0 + p) * TV + e8 * 8);
            #pragma unroll
            for (int k = 0; k < 8; ++k) {
                int j = e8 * 8 + k;
                int t = j / 25, u = j % 25;
                sA[p * 2048 + t * 32 + u] = (unsigned short)vv[k];
            }
        }
    }
    // stage attnT (scatter to u-stride 32)
    #pragma unroll
    for (int i = 0; i < 2; ++i) {
        int task = i * 256 + tid;              // 4*79 = 316
        if (task < 316) {
            int p = task / 79, e8 = task % 79;
            bshort8 vv = *(const bshort8*)(attnT + (size_t)(no0 + p) * ATS + e8 * 8);
            #pragma unroll
            for (int k = 0; k < 8; ++k) {
                int idx = e8 * 8 + k;
                if (idx < VV) {
                    int v = idx / 25, u = idx % 25;
                    sB[p * 1024 + v * 32 + u] = (unsigned short)vv[k];
                }
            }
        }
    }
    __syncthreads();
    int p = tid >> 6, lane = tid & 63;
    int quad = lane >> 4, c16 = lane & 15;
    const unsigned short* pA = sA + p * 2048;
    const unsigned short* pB = sB + p * 1024;
    bshort8 a[4], b[2];
    #pragma unroll
    for (int mt = 0; mt < 4; ++mt) a[mt] = *(const bshort8*)&pA[(mt * 16 + c16) * 32 + quad * 8];
    #pragma unroll
    for (int nt = 0; nt < 2; ++nt) b[nt] = *(const bshort8*)&pB[(nt * 16 + c16) * 32 + quad * 8];
    f32x4 acc[4][2];
    #pragma unroll
    for (int mt = 0; mt < 4; ++mt)
        #pragma unroll
        for (int nt = 0; nt < 2; ++nt)
            acc[mt][nt] = __builtin_amdgcn_mfma_f32_16x16x32_bf16(a[mt], b[nt], (f32x4){0,0,0,0}, 0, 0, 0);
    __syncthreads();     // frag reads done; alias sO
    float* pO = sO + p * 1792;
    #pragma unroll
    for (int mt = 0; mt < 4; ++mt)
        #pragma unroll
        for (int nt = 0; nt < 2; ++nt) {
            int v = nt * 16 + c16;
            if (v < V_) {
                #pragma unroll
                for (int r = 0; r < 4; ++r) {
                    int t = mt * 16 + quad * 4 + r;
                    pO[t * 28 + v] = acc[mt][nt][r];
                }
            }
        }
    __syncthreads();
    #pragma unroll
    for (int i = 0; i < 25; ++i) {
        int idx = i * 256 + tid;               // 6400
        int p2 = idx / TV, rem = idx % TV;
        int t = rem / 25, v = rem % 25;
        out[(size_t)(no0 + p2) * TV + rem] = sO[p2 * 1792 + t * 28 + v];
    }
}

extern "C" void kernel_launch(void* const* d_in, const int* in_sizes, int n_in,
                              void* d_out, int out_size, void* d_ws, size_t ws_size,
                              hipStream_t stream) {
    const float* x  = (const float*)d_in[0];
    const float* A  = (const float*)d_in[1];
    const float* w1 = (const float*)d_in[2];
    const float* b1 = (const float*)d_in[3];
    const float* w2 = (const float*)d_in[4];
    const float* b2 = (const float*)d_in[5];
    const float* w3 = (const float*)d_in[6];
    const float* b3 = (const float*)d_in[7];
    const float* w4 = (const float*)d_in[8];
    const float* b4 = (const float*)d_in[9];
    const int* alpha_p = (const int*)d_in[11];
    float* out = (float*)d_out;

    float* ws = (float*)d_ws;
    float* xm = ws;                                            // 409600 f
    float* x1 = ws + 409600;                                   // 51200 f
    float* x2 = ws + 460800;                                   // 51200 f
    unsigned short* attnT = (unsigned short*)(ws + 512000);    // 16384*640 us
    unsigned short* w3f   = attnT + (size_t)16384 * ATS;       // 65536 us
    unsigned short* xT    = w3f + 65536;                       // 26214400 us
    unsigned short* x3    = xT + (size_t)26214400;             // 26214400 us
    unsigned short* w4f   = x3 + (size_t)26214400;             // 16384 us

    k_cvt_w3f<<<32, 256, 0, stream>>>(w3, w3f);
    k_cvt_w4f<<<4, 256, 0, stream>>>(w4, w4f);
    k_xpose<<<dim3(N_, 4, 25), 256, 0, stream>>>(x, xT);
    k_mean<<<(N_ * CI * V_ + 255) / 256, 256, 0, stream>>>(x, xm);
    k_x1x2<<<N_, 256, 0, stream>>>(xm, w1, b1, w2, b2, x1, x2);
    k_attn<<<dim3(N_, 8), 256, 0, stream>>>(x1, x2, w4f, b4, A, alpha_p, attnT);
    k_gemm1<<<dim3(N_, 25), 256, 0, stream>>>(xT, w3f, b3, x3);
    k_contract<<<4096, 256, 0, stream>>>(x3, attnT, out);
}

// Round 2
// 323.188 us; speedup vs baseline: 1.2574x; 1.0963x over previous
//
#include <hip/hip_runtime.h>

#define N_  64
#define CI  256
#define CO  256
#define CR  32
#define T_  64
#define V_  25
#define TV  (T_*V_)   // 1600
#define VV  (V_*V_)   // 625
#define ATS 640       // attnT per-(n,o) stride in shorts (625 used, pad to 16B-aligned)

typedef __attribute__((ext_vector_type(8))) short bshort8;
typedef __attribute__((ext_vector_type(4))) float f32x4;

__device__ inline unsigned short f2bf(float f) {
    unsigned int u = __float_as_uint(f);
    return (unsigned short)((u + 0x7FFFu + ((u >> 16) & 1u)) >> 16);
}

// ---------------- K0: w3 + w4 -> bf16 in MFMA A-fragment order ----------------
// w3f[((ot*8+ks)*64+lane)*8+i] = w3[ot*16+(lane&15)][ks*32+(lane>>4)*8+i]
// w4f[(ot*64+lane)*8+i]        = w4[ot*16+(lane&15)][(lane>>4)*8+i]
__global__ __launch_bounds__(256) void k_cvt_w(const float* __restrict__ w3,
                                               const float* __restrict__ w4,
                                               unsigned short* __restrict__ w3f,
                                               unsigned short* __restrict__ w4f) {
    int b = blockIdx.x;
    if (b < 32) {
        int f = b * 256 + threadIdx.x;             // 0..8191
        int lane = f & 63;
        int ks = (f >> 6) & 7;
        int ot = f >> 9;
        const float* src = w3 + (size_t)(ot * 16 + (lane & 15)) * CI + ks * 32 + (lane >> 4) * 8;
        bshort8 v;
        #pragma unroll
        for (int i = 0; i < 8; ++i) v[i] = (short)f2bf(src[i]);
        *(bshort8*)(w3f + (size_t)f * 8) = v;
    } else {
        int f = (b - 32) * 256 + threadIdx.x;      // 0..1023
        int lane = f & 63;
        int ot = f >> 6;
        const float* src = w4 + (size_t)(ot * 16 + (lane & 15)) * CR + (lane >> 4) * 8;
        bshort8 v;
        #pragma unroll
        for (int i = 0; i < 8; ++i) v[i] = (short)f2bf(src[i]);
        *(bshort8*)(w4f + (size_t)f * 8) = v;
    }
}

// ---------------- K1: xm[n,c,v] = mean_t x[n,c,t,v] ----------------
__global__ __launch_bounds__(256) void k_mean(const float* __restrict__ x,
                                              float* __restrict__ xm) {
    int idx = blockIdx.x * 256 + threadIdx.x;
    if (idx >= N_ * CI * V_) return;
    int v  = idx % V_;
    int nc = idx / V_;
    const float* p = x + (size_t)nc * TV + v;
    float s = 0.f;
    for (int t = 0; t < T_; ++t) s += p[t * V_];
    xm[idx] = s * (1.f / T_);
}

// ---------------- K2: x1/x2 = w1/w2 @ xm + b ----------------
__global__ __launch_bounds__(256) void k_x1x2(const float* __restrict__ xm,
                                              const float* __restrict__ w1,
                                              const float* __restrict__ b1,
                                              const float* __restrict__ w2,
                                              const float* __restrict__ b2,
                                              float* __restrict__ x1,
                                              float* __restrict__ x2) {
    int n = blockIdx.x;
    __shared__ float s_xm[CI * V_];
    const float4* src = (const float4*)(xm + (size_t)n * CI * V_);
    for (int i = threadIdx.x; i < CI * V_ / 4; i += 256) ((float4*)s_xm)[i] = src[i];
    __syncthreads();
    for (int idx = threadIdx.x; idx < CR * V_; idx += 256) {
        int r = idx / V_, v = idx % V_;
        float a1 = 0.f, a2 = 0.f;
        for (int c = 0; c < CI; ++c) {
            float xv = s_xm[c * V_ + v];
            a1 += w1[r * CI + c] * xv;
            a2 += w2[r * CI + c] * xv;
        }
        x1[n * CR * V_ + idx] = a1 + b1[r];
        x2[n * CR * V_ + idx] = a2 + b2[r];
    }
}

// ---------------- K3: attnT bf16 via MFMA, aff computed in registers ----------------
// attnT[v][u] at uv=v*25+u: (sum_r w4[o,r]*tanh(x1[r,u]-x2[r,v]) + b4[o])*alpha + A[u,v]
// wave-task = 4 o-tiles (64 o) x 5 uv-tiles (80 uv cols); grid (n, 8) -> 512 blocks
__global__ __launch_bounds__(256) void k_attn(const float* __restrict__ x1,
                                              const float* __restrict__ x2,
                                              const unsigned short* __restrict__ w4f,
                                              const float* __restrict__ b4,
                                              const float* __restrict__ A,
                                              const int* __restrict__ alpha_p,
                                              unsigned short* __restrict__ attnT) {
    int n = blockIdx.x;
    __shared__ float s_x1[CR * V_];
    __shared__ float s_x2[CR * V_];
    __shared__ float s_A[VV];
    int tid = threadIdx.x;
    float alpha = (float)alpha_p[0];
    for (int i = tid; i < CR * V_; i += 256) {
        s_x1[i] = x1[n * CR * V_ + i];
        s_x2[i] = x2[n * CR * V_ + i];
    }
    for (int i = tid; i < VV; i += 256) s_A[i] = A[i];
    __syncthreads();
    int wave = tid >> 6, lane = tid & 63;
    int task = blockIdx.y * 4 + wave;       // 0..31
    int og   = task & 3;                    // o-group of 64 (4 MFMA o-tiles)
    int ug   = task >> 2;                   // uv-group of 5 uv-tiles (80 cols)
    int o0   = og * 64;
    int quad = lane >> 4, c16 = lane & 15;
    bshort8 a[4];
    #pragma unroll
    for (int ot = 0; ot < 4; ++ot)
        a[ot] = *(const bshort8*)(w4f + (size_t)(((og * 4) + ot) * 64 + lane) * 8);
    float4 bv[4];
    #pragma unroll
    for (int ot = 0; ot < 4; ++ot)
        bv[ot] = *(const float4*)(b4 + o0 + ot * 16 + quad * 4);
    int r0 = quad * 8;
    #pragma unroll
    for (int it = 0; it < 5; ++it) {
        int uv0 = (ug * 5 + it) * 16;
        int uvc = uv0 + c16;
        bool valid = uvc < VV;
        int uvcc = valid ? uvc : (VV - 1);
        int u = uvcc % V_, v = uvcc / V_;
        bshort8 b;
        #pragma unroll
        for (int i = 0; i < 8; ++i) {
            float d = s_x1[(r0 + i) * V_ + u] - s_x2[(r0 + i) * V_ + v];
            b[i] = (short)f2bf(tanhf(d));
        }
        float Auv = s_A[u * V_ + v];
        f32x4 acc[4];
        #pragma unroll
        for (int ot = 0; ot < 4; ++ot)
            acc[ot] = __builtin_amdgcn_mfma_f32_16x16x32_bf16(a[ot], b, (f32x4){0,0,0,0}, 0, 0, 0);
        if (valid) {
            #pragma unroll
            for (int ot = 0; ot < 4; ++ot) {
                #pragma unroll
                for (int r = 0; r < 4; ++r) {
                    int o = o0 + ot * 16 + quad * 4 + r;
                    float bval = (r == 0) ? bv[ot].x : (r == 1) ? bv[ot].y
                               : (r == 2) ? bv[ot].z : bv[ot].w;
                    attnT[(size_t)(n * CO + o) * ATS + uvc] =
                        f2bf((acc[ot][r] + bval) * alpha + Auv);
                }
            }
        }
    }
}

// ---------------- K4: MFMA GEMM full-o, staging directly from x (fp32) ----------------
// block = (n, j-tile 64); o = 256. Transpose+cvt happens during LDS staging:
// sB[j][c] = bf16(x[n][c][j0+j]), octet swizzle f = (c>>3) ^ (j&7) ^ ((j>>2)&7).
__global__ __launch_bounds__(256) void k_gemm1(const float* __restrict__ x,
                                               const unsigned short* __restrict__ w3f,
                                               const float* __restrict__ b3,
                                               unsigned short* __restrict__ x3) {
    int n = blockIdx.x, j0 = blockIdx.y * 64;
    __shared__ unsigned short sB[64 * 256];
    int tid  = threadIdx.x;
    int lane = tid & 63, wave = tid >> 6;
    const float* gx = x + (size_t)n * CI * TV + j0;
    // 4096 float4 tasks: task = c*16 + chunk (chunk = 4-j group) -> coalesced 256B rows
    for (int i = 0; i < 16; ++i) {
        int task = i * 256 + tid;
        int c = task >> 4, chunk = task & 15;
        float4 v = *(const float4*)(gx + (size_t)c * TV + chunk * 4);
        int g0 = c >> 3, cl = c & 7;
        #pragma unroll
        for (int k = 0; k < 4; ++k) {
            int j = chunk * 4 + k;
            int f = g0 ^ (j & 7) ^ ((j >> 2) & 7);
            float val = (k == 0) ? v.x : (k == 1) ? v.y : (k == 2) ? v.z : v.w;
            sB[j * 256 + f * 8 + cl] = f2bf(val);
        }
    }
    __syncthreads();
    int quad = lane >> 4, c16 = lane & 15;
    const bshort8* Af = (const bshort8*)w3f;
    f32x4 acc[4][4];
    #pragma unroll
    for (int mt = 0; mt < 4; ++mt)
        #pragma unroll
        for (int nt = 0; nt < 4; ++nt) acc[mt][nt] = (f32x4){0,0,0,0};
    #pragma unroll
    for (int ks = 0; ks < 8; ++ks) {
        bshort8 b[4], a[4];
        #pragma unroll
        for (int nt = 0; nt < 4; ++nt) {
            int rB = nt * 16 + c16;
            int cidx = ks * 4 + quad;
            int f = cidx ^ (rB & 7) ^ ((rB >> 2) & 7);
            b[nt] = *(const bshort8*)(&sB[rB * 256 + f * 8]);
        }
        #pragma unroll
        for (int mt = 0; mt < 4; ++mt)
            a[mt] = Af[(size_t)(((wave * 4 + mt) * 8 + ks) * 64) + lane];
        #pragma unroll
        for (int mt = 0; mt < 4; ++mt)
            #pragma unroll
            for (int nt = 0; nt < 4; ++nt)
                acc[mt][nt] = __builtin_amdgcn_mfma_f32_16x16x32_bf16(a[mt], b[nt], acc[mt][nt], 0, 0, 0);
    }
    __syncthreads();                      // sB free; alias as epilogue buffer
    unsigned short* eS = sB;              // 128 rows x stride 72 shorts
    #pragma unroll
    for (int pass = 0; pass < 2; ++pass) {
        if ((wave >> 1) == pass) {
            #pragma unroll
            for (int mt = 0; mt < 4; ++mt) {
                int o = wave * 64 + mt * 16 + quad * 4;
                float4 bvv = *(const float4*)(b3 + o);
                int ol = (wave & 1) * 64 + mt * 16 + quad * 4;
                #pragma unroll
                for (int nt = 0; nt < 4; ++nt) {
                    int jc = nt * 16 + c16;
                    eS[(ol + 0) * 72 + jc] = f2bf(acc[mt][nt][0] + bvv.x);
                    eS[(ol + 1) * 72 + jc] = f2bf(acc[mt][nt][1] + bvv.y);
                    eS[(ol + 2) * 72 + jc] = f2bf(acc[mt][nt][2] + bvv.z);
                    eS[(ol + 3) * 72 + jc] = f2bf(acc[mt][nt][3] + bvv.w);
                }
            }
        }
        __syncthreads();
        #pragma unroll
        for (int i = 0; i < 4; ++i) {
            int task = i * 256 + tid;         // 1024
            int orow = task >> 3, seg = task & 7;
            bshort8 vv = *(const bshort8*)&eS[orow * 72 + seg * 8];
            *(bshort8*)(x3 + (size_t)(n * CO + pass * 128 + orow) * TV + j0 + seg * 8) = vv;
        }
        __syncthreads();
    }
}

// ---------------- K5: MFMA contraction: out[t,v] = sum_u x3[t,u] * attnT[v,u] ----------------
// block = 4 (n,o) pairs, one wave each; u padded to 32 (zeros in A and B pads)
__global__ __launch_bounds__(256) void k_contract(const unsigned short* __restrict__ x3,
                                                  const unsigned short* __restrict__ attnT,
                                                  float* __restrict__ out) {
    int no0 = blockIdx.x * 4;
    __shared__ __align__(16) unsigned char smem[28672];
    unsigned short* sA = (unsigned short*)smem;            // 4 x [64][32]
    unsigned short* sB = (unsigned short*)(smem + 16384);  // 4 x [32][32]
    float*          sO = (float*)smem;                     // 4 x [64][28]
    int tid = threadIdx.x;
    #pragma unroll
    for (int i = 0; i < 7; ++i) {
        int task = i * 256 + tid;              // 4*64*7 = 1792
        if (task < 1792) {
            int p = task / 448, rem = task % 448;
            sA[p * 2048 + (rem / 7) * 32 + 25 + rem % 7] = 0;
        }
    }
    {
        int task = tid;                         // 4*25*7 = 700
        for (int i = 0; i < 3; ++i, task += 256)
            if (task < 700) {
                int p = task / 175, rem = task % 175;
                sB[p * 1024 + (rem / 7) * 32 + 25 + rem % 7] = 0;
            }
    }
    #pragma unroll
    for (int i = 0; i < 4; ++i) {
        int task = i * 256 + tid;              // 800
        if (task < 800) {
            int p = task / 200, e8 = task % 200;
            bshort8 vv = *(const bshort8*)(x3 + (size_t)(no0 + p) * TV + e8 * 8);
            #pragma unroll
            for (int k = 0; k < 8; ++k) {
                int j = e8 * 8 + k;
                int t = j / 25, u = j % 25;
                sA[p * 2048 + t * 32 + u] = (unsigned short)vv[k];
            }
        }
    }
    #pragma unroll
    for (int i = 0; i < 2; ++i) {
        int task = i * 256 + tid;              // 4*79 = 316
        if (task < 316) {
            int p = task / 79, e8 = task % 79;
            bshort8 vv = *(const bshort8*)(attnT + (size_t)(no0 + p) * ATS + e8 * 8);
            #pragma unroll
            for (int k = 0; k < 8; ++k) {
                int idx = e8 * 8 + k;
                if (idx < VV) {
                    int v = idx / 25, u = idx % 25;
                    sB[p * 1024 + v * 32 + u] = (unsigned short)vv[k];
                }
            }
        }
    }
    __syncthreads();
    int p = tid >> 6, lane = tid & 63;
    int quad = lane >> 4, c16 = lane & 15;
    const unsigned short* pA = sA + p * 2048;
    const unsigned short* pB = sB + p * 1024;
    bshort8 a[4], b[2];
    #pragma unroll
    for (int mt = 0; mt < 4; ++mt) a[mt] = *(const bshort8*)&pA[(mt * 16 + c16) * 32 + quad * 8];
    #pragma unroll
    for (int nt = 0; nt < 2; ++nt) b[nt] = *(const bshort8*)&pB[(nt * 16 + c16) * 32 + quad * 8];
    f32x4 acc[4][2];
    #pragma unroll
    for (int mt = 0; mt < 4; ++mt)
        #pragma unroll
        for (int nt = 0; nt < 2; ++nt)
            acc[mt][nt] = __builtin_amdgcn_mfma_f32_16x16x32_bf16(a[mt], b[nt], (f32x4){0,0,0,0}, 0, 0, 0);
    __syncthreads();     // frag reads done; alias sO
    float* pO = sO + p * 1792;
    #pragma unroll
    for (int mt = 0; mt < 4; ++mt)
        #pragma unroll
        for (int nt = 0; nt < 2; ++nt) {
            int v = nt * 16 + c16;
            if (v < V_) {
                #pragma unroll
                for (int r = 0; r < 4; ++r) {
                    int t = mt * 16 + quad * 4 + r;
                    pO[t * 28 + v] = acc[mt][nt][r];
                }
            }
        }
    __syncthreads();
    #pragma unroll
    for (int i = 0; i < 25; ++i) {
        int idx = i * 256 + tid;               // 6400
        int p2 = idx / TV, rem = idx % TV;
        int t = rem / 25, v = rem % 25;
        out[(size_t)(no0 + p2) * TV + rem] = sO[p2 * 1792 + t * 28 + v];
    }
}

extern "C" void kernel_launch(void* const* d_in, const int* in_sizes, int n_in,
                              void* d_out, int out_size, void* d_ws, size_t ws_size,
                              hipStream_t stream) {
    const float* x  = (const float*)d_in[0];
    const float* A  = (const float*)d_in[1];
    const float* w1 = (const float*)d_in[2];
    const float* b1 = (const float*)d_in[3];
    const float* w2 = (const float*)d_in[4];
    const float* b2 = (const float*)d_in[5];
    const float* w3 = (const float*)d_in[6];
    const float* b3 = (const float*)d_in[7];
    const float* w4 = (const float*)d_in[8];
    const float* b4 = (const float*)d_in[9];
    const int* alpha_p = (const int*)d_in[11];
    float* out = (float*)d_out;

    float* ws = (float*)d_ws;
    float* xm = ws;                                            // 409600 f
    float* x1 = ws + 409600;                                   // 51200 f
    float* x2 = ws + 460800;                                   // 51200 f
    unsigned short* attnT = (unsigned short*)(ws + 512000);    // 16384*640 us
    unsigned short* w3f   = attnT + (size_t)16384 * ATS;       // 65536 us
    unsigned short* w4f   = w3f + 65536;                       // 16384 us
    unsigned short* x3    = w4f + 16384;                       // 26214400 us

    k_cvt_w<<<36, 256, 0, stream>>>(w3, w4, w3f, w4f);
    k_mean<<<(N_ * CI * V_ + 255) / 256, 256, 0, stream>>>(x, xm);
    k_x1x2<<<N_, 256, 0, stream>>>(xm, w1, b1, w2, b2, x1, x2);
    k_attn<<<dim3(N_, 8), 256, 0, stream>>>(x1, x2, w4f, b4, A, alpha_p, attnT);
    k_gemm1<<<dim3(N_, 25), 256, 0, stream>>>(x, w3f, b3, x3);
    k_contract<<<4096, 256, 0, stream>>>(x3, attnT, out);
}